// Round 16
// baseline (374.771 us; speedup 1.0000x reference)
//
#include <hip/hip_runtime.h>
#include <hip/hip_bf16.h>
#include <hip/hip_cooperative_groups.h>
namespace cg = cooperative_groups;

#define B_   64
#define N_   512
#define D_   128

typedef float f32x4  __attribute__((ext_vector_type(4)));
typedef _Float16 f16x8 __attribute__((ext_vector_type(8)));

static __device__ __forceinline__ unsigned pkrtz(float x, float y) {
    return __builtin_bit_cast(unsigned, __builtin_amdgcn_cvt_pkrtz(x, y));
}
static __device__ __forceinline__ short f2h(float x) {
    _Float16 h = (_Float16)x;
    return __builtin_bit_cast(short, h);
}
static __device__ __forceinline__ float h2f(short s) {
    return (float)__builtin_bit_cast(_Float16, s);
}
static __device__ __forceinline__ float fast_tanh(float x) {
    float e = __expf(2.f * x);
    return 1.f - 2.f * __builtin_amdgcn_rcpf(e + 1.f);
}
static __device__ __forceinline__ void pk_add16(unsigned& acc, unsigned v) {
    asm("v_pk_add_f16 %0, %1, %0" : "+v"(acc) : "v"(v));
}

#define LDA1 264   // K=256 + 8 pad (fp16)
#define LDA2 136   // K=128 + 8 pad

// ===========================================================================
// Fused cooperative kernel: 512 blocks x 512 threads, 2 blocks/CU co-resident.
// Block owns 64 nodes of one batch (XCD-pinned) through all 3 phases.
//  P0: convert own lib rows fp32->fp16; blocks 0..11 pack B-frags; 12..27 zero out
//  P1: gemm1 (gather libh + word | K=256 f16 MFMA) -> baseh, t1h
//  P2: gemm2 (gather t1h | K=128 MFMA; tanh; mask-reduce; @w2; atomic out)
// ===========================================================================
__global__ __launch_bounds__(512, 4) void fused(const float* __restrict__ word,
                                                const int* __restrict__ nbrL,
                                                const float* __restrict__ lib,
                                                const int* __restrict__ nbr,
                                                const float* __restrict__ mask,
                                                const float* __restrict__ w2,
                                                const float* __restrict__ enc1,
                                                const float* __restrict__ wgt,
                                                const float* __restrict__ enc2,
                                                short* __restrict__ libh,
                                                short* __restrict__ Bp1,
                                                short* __restrict__ Bp2,
                                                short* __restrict__ baseh,
                                                short* __restrict__ t1h,
                                                float* __restrict__ out) {
    __shared__ short sA[64 * LDA1];
    __shared__ int sIdx[64 * 16];
    __shared__ float pred[4 * 128];
    __shared__ float ptot[128];
    __shared__ float smask[64];

    const int t = threadIdx.x;
    const int hw = blockIdx.x;
    const int logical = ((hw & 7) << 6) + (hw >> 3);   // XCD k <- batches [8k,8k+8)
    const int b = logical >> 3;
    const int node0 = logical * 64;                    // global node row base

    // ---------------- P0: convert own lib rows + pack + zero ----------------
    {
        const float* src = lib + (size_t)node0 * D_ + t * 16;
        unsigned o[8];
#pragma unroll
        for (int q = 0; q < 4; ++q) {
            float4 v = *(const float4*)&src[q * 4];
            o[q * 2]     = pkrtz(v.x, v.y);
            o[q * 2 + 1] = pkrtz(v.z, v.w);
        }
        short* dst = libh + (size_t)node0 * D_ + t * 16;
        *(int4*)&dst[0] = *(int4*)o;
        *(int4*)&dst[8] = *(int4*)(o + 4);
    }
    if (hw < 12) {
        int ptid = hw * 512 + t;   // 0..6143
        short o8[8];
        if (ptid < 4096) {
            int l = ptid & 63, nt = (ptid >> 6) & 7, ks = ptid >> 9;   // ks 0..7
            int k0 = ks * 32 + (l >> 4) * 8;
            int col = nt * 16 + (l & 15);
#pragma unroll
            for (int j = 0; j < 8; ++j) {
                int r = k0 + j;
                float v = (r < 128) ? enc1[r * 128 + col] : wgt[(r - 128) * 128 + col] * 0.0625f;
                o8[j] = f2h(v);
            }
            *(int4*)&Bp1[(size_t)ptid * 8] = *(int4*)o8;
        } else {
            int t2 = ptid - 4096;
            int l = t2 & 63, nt = (t2 >> 6) & 7, ks = t2 >> 9;         // ks 0..3
            int k0 = ks * 32 + (l >> 4) * 8;
            int col = nt * 16 + (l & 15);
#pragma unroll
            for (int j = 0; j < 8; ++j) o8[j] = f2h(enc2[(k0 + j) * 128 + col] * 0.0625f);
            *(int4*)&Bp2[(size_t)t2 * 8] = *(int4*)o8;
        }
    } else if (hw < 28) {
        out[(hw - 12) * 512 + t] = 0.f;   // 16*512 = 8192 = B_*D_
    }
    __threadfence();
    cg::this_grid().sync();

    // ---------------- P1: gemm1 ----------------
    if (t < 256) *(int4*)&sIdx[t * 4] = *(const int4*)&nbrL[(size_t)node0 * 16 + t * 4];
    {   // stage word: 8 thr/row x 16 elems
        const int row = t >> 3, cgp = t & 7;
        const float* wr = word + (size_t)(node0 + row) * D_ + cgp * 16;
        unsigned o[8];
#pragma unroll
        for (int q = 0; q < 4; ++q) {
            float4 v = *(const float4*)&wr[q * 4];
            o[q * 2]     = pkrtz(v.x, v.y);
            o[q * 2 + 1] = pkrtz(v.z, v.w);
        }
        *(int4*)&sA[row * LDA1 + cgp * 16]     = *(int4*)o;
        *(int4*)&sA[row * LDA1 + cgp * 16 + 8] = *(int4*)(o + 4);
    }
    __syncthreads();

    const char* libhB = (const char*)libh + (size_t)b * N_ * 256;   // 256B/row
#pragma unroll
    for (int p = 0; p < 2; ++p) {
        const int row = p * 32 + (t >> 4), lg = t & 15;
        int idx[16];
#pragma unroll
        for (int q = 0; q < 4; ++q) *(int4*)&idx[q * 4] = *(const int4*)&sIdx[row * 16 + q * 4];
        unsigned a0 = 0, a1 = 0, a2 = 0, a3 = 0;
#pragma unroll
        for (int nb = 0; nb < 16; ++nb) {
            int4 d = *(const int4*)(libhB + ((unsigned)idx[nb] << 8) + lg * 16);
            pk_add16(a0, (unsigned)d.x);
            pk_add16(a1, (unsigned)d.y);
            pk_add16(a2, (unsigned)d.z);
            pk_add16(a3, (unsigned)d.w);
        }
        unsigned o[4] = { a0, a1, a2, a3 };   // raw sums; /16 folded into Bp1 tail
        *(int4*)&sA[row * LDA1 + 128 + lg * 8] = *(int4*)o;
    }
    __syncthreads();

    const int w = t >> 6, l = t & 63;
    const int rt = w >> 1, chh = w & 1;
    const int arow = rt * 16 + (l & 15);
    const int r0 = rt * 16 + (l >> 4) * 4, cl = l & 15;

    {
        f32x4 acc[4];
#pragma unroll
        for (int j = 0; j < 4; ++j) acc[j] = (f32x4)0.f;
#pragma unroll
        for (int ks = 0; ks < 8; ++ks) {
            f16x8 a = *(const f16x8*)&sA[arow * LDA1 + ks * 32 + (l >> 4) * 8];
#pragma unroll
            for (int j = 0; j < 4; ++j) {
                const int nt = chh * 4 + j;
                f16x8 bb = *(const f16x8*)&Bp1[((size_t)(ks * 8 + nt) * 64 + l) * 8];
                acc[j] = __builtin_amdgcn_mfma_f32_16x16x32_f16(a, bb, acc[j], 0, 0, 0);
            }
        }
#pragma unroll
        for (int j = 0; j < 4; ++j) {
            const int col = (chh * 4 + j) * 16 + cl;
#pragma unroll
            for (int r = 0; r < 4; ++r) {
                size_t o = (size_t)(node0 + r0 + r) * D_ + col;
                float v = acc[j][r];
                baseh[o] = f2h(v);
                t1h[o]   = f2h(fast_tanh(v));
            }
        }
    }
    __threadfence();
    cg::this_grid().sync();

    // ---------------- P2: gemm2 ----------------
    if (t < 256) *(int4*)&sIdx[t * 4] = *(const int4*)&nbr[(size_t)node0 * 16 + t * 4];
    if (t >= 256 && t < 320) smask[t - 256] = mask[node0 + (t - 256)];
    __syncthreads();

    const char* t1B = (const char*)t1h + (size_t)b * N_ * 256;
#pragma unroll
    for (int p = 0; p < 2; ++p) {
        const int row = p * 32 + (t >> 4), lg = t & 15;
        int idx[16];
#pragma unroll
        for (int q = 0; q < 4; ++q) *(int4*)&idx[q * 4] = *(const int4*)&sIdx[row * 16 + q * 4];
        unsigned a0 = 0, a1 = 0, a2 = 0, a3 = 0;
#pragma unroll
        for (int nb = 0; nb < 16; ++nb) {
            int4 d = *(const int4*)(t1B + ((unsigned)idx[nb] << 8) + lg * 16);
            pk_add16(a0, (unsigned)d.x);
            pk_add16(a1, (unsigned)d.y);
            pk_add16(a2, (unsigned)d.z);
            pk_add16(a3, (unsigned)d.w);
        }
        unsigned o[4] = { a0, a1, a2, a3 };   // /16 folded into Bp2
        *(int4*)&sA[row * LDA2 + lg * 8] = *(int4*)o;
    }
    __syncthreads();

    {
        f32x4 acc[4];
#pragma unroll
        for (int j = 0; j < 4; ++j) acc[j] = (f32x4)0.f;
#pragma unroll
        for (int ks = 0; ks < 4; ++ks) {
            f16x8 a = *(const f16x8*)&sA[arow * LDA2 + ks * 32 + (l >> 4) * 8];
#pragma unroll
            for (int j = 0; j < 4; ++j) {
                const int nt = chh * 4 + j;
                f16x8 bb = *(const f16x8*)&Bp2[((size_t)(ks * 8 + nt) * 64 + l) * 8];
                acc[j] = __builtin_amdgcn_mfma_f32_16x16x32_f16(a, bb, acc[j], 0, 0, 0);
            }
        }
#pragma unroll
        for (int j = 0; j < 4; ++j) {
            const int col = (chh * 4 + j) * 16 + cl;
            float s = 0.f;
#pragma unroll
            for (int r = 0; r < 4; ++r) {
                size_t o = (size_t)(node0 + r0 + r) * D_ + col;
                float v = fast_tanh(h2f(baseh[o]) + acc[j][r]);
                s += v * smask[r0 + r];
            }
            s += __shfl_xor(s, 16);
            s += __shfl_xor(s, 32);
            if (l < 16) pred[rt * 128 + col] = s;
        }
    }
    __syncthreads();
    if (t < 128) ptot[t] = pred[t] + pred[128 + t] + pred[256 + t] + pred[384 + t];
    __syncthreads();
    if (t < 128) {
        float a2 = 0.f;
#pragma unroll 4
        for (int f = 0; f < 128; ++f) a2 += ptot[f] * w2[f * 128 + t];
        atomicAdd(&out[b * 128 + t], a2);
    }
}

// ===========================================================================
// Fallback path: R14's proven 3-kernel pipeline (48.3 us)
// ===========================================================================
#define NPB  16
#define G1F  ((B_*N_)/NPB)

__global__ __launch_bounds__(256) void fb_prep(const float* __restrict__ lib,
                                               const float* __restrict__ enc1,
                                               const float* __restrict__ wgt,
                                               const float* __restrict__ enc2,
                                               short* __restrict__ libh,
                                               short* __restrict__ Bp1,
                                               short* __restrict__ Bp2,
                                               float* __restrict__ out) {
    const int blk = blockIdx.x;
    if (blk < 1024) {
        const size_t g = ((size_t)blk * 256 + threadIdx.x) * 16;
        unsigned o[8];
#pragma unroll
        for (int q = 0; q < 4; ++q) {
            float4 v = *(const float4*)&lib[g + q * 4];
            o[q * 2]     = pkrtz(v.x, v.y);
            o[q * 2 + 1] = pkrtz(v.z, v.w);
        }
        *(int4*)&libh[g]     = *(int4*)o;
        *(int4*)&libh[g + 8] = *(int4*)(o + 4);
        return;
    }
    int tid = (blk - 1024) * 256 + threadIdx.x;
    out[tid] = 0.f;
    short o8[8];
    if (tid < 4096) {
        int l = tid & 63, nt = (tid >> 6) & 7, ks = tid >> 9;
        int k0 = ks * 32 + (l >> 4) * 8;
        int col = nt * 16 + (l & 15);
#pragma unroll
        for (int j = 0; j < 8; ++j) {
            int r = k0 + j;
            float v = (r < 128) ? enc1[r * 128 + col] : wgt[(r - 128) * 128 + col] * 0.0625f;
            o8[j] = f2h(v);
        }
        *(int4*)&Bp1[(size_t)tid * 8] = *(int4*)o8;
    } else if (tid < 6144) {
        int t2 = tid - 4096;
        int l = t2 & 63, nt = (t2 >> 6) & 7, ks = t2 >> 9;
        int k0 = ks * 32 + (l >> 4) * 8;
        int col = nt * 16 + (l & 15);
#pragma unroll
        for (int j = 0; j < 8; ++j) o8[j] = f2h(enc2[(k0 + j) * 128 + col] * 0.0625f);
        *(int4*)&Bp2[(size_t)t2 * 8] = *(int4*)o8;
    }
}

static __device__ __forceinline__ int fb_swz() {
    const int hw = blockIdx.x;
    return ((hw & 7) << 8) + (hw >> 3);
}

__global__ __launch_bounds__(256) void fb_gemm1(const float* __restrict__ word,
                                                const int* __restrict__ nbrL,
                                                const short* __restrict__ libh,
                                                const short* __restrict__ Bp1,
                                                short* __restrict__ baseh,
                                                short* __restrict__ t1) {
    __shared__ short sA[NPB * LDA1];
    __shared__ int sIdx[NPB * 16];
    const int tid = threadIdx.x;
    const int blk = fb_swz();
    const int b = blk >> 5;
    const int node0 = blk * NPB;

    if (tid < 64) *(int4*)&sIdx[tid * 4] = *(const int4*)&nbrL[(size_t)node0 * 16 + tid * 4];
    __syncthreads();

    const int row = tid >> 4, lg = tid & 15;
    {
        const float* wr = word + (size_t)(node0 + row) * D_ + lg * 8;
        float4 v0 = *(const float4*)&wr[0];
        float4 v1 = *(const float4*)&wr[4];
        unsigned o[4] = { pkrtz(v0.x, v0.y), pkrtz(v0.z, v0.w),
                          pkrtz(v1.x, v1.y), pkrtz(v1.z, v1.w) };
        *(int4*)&sA[row * LDA1 + lg * 8] = *(int4*)o;
    }
    {
        int idxr[16];
#pragma unroll
        for (int q = 0; q < 4; ++q) *(int4*)&idxr[q * 4] = *(const int4*)&sIdx[row * 16 + q * 4];
        const char* libB = (const char*)libh + (size_t)b * N_ * D_ * 2 + lg * 16;
        unsigned a0 = 0, a1 = 0, a2 = 0, a3 = 0;
#pragma unroll
        for (int nb = 0; nb < 16; ++nb) {
            int4 d = *(const int4*)(libB + ((unsigned)idxr[nb] << 8));
            pk_add16(a0, (unsigned)d.x);
            pk_add16(a1, (unsigned)d.y);
            pk_add16(a2, (unsigned)d.z);
            pk_add16(a3, (unsigned)d.w);
        }
        unsigned o[4] = { a0, a1, a2, a3 };
        *(int4*)&sA[row * LDA1 + 128 + lg * 8] = *(int4*)o;
    }
    __syncthreads();

    const int w = tid >> 6, l = tid & 63;
    f32x4 acc[2];
    acc[0] = (f32x4)0.f; acc[1] = (f32x4)0.f;
    const int arow = l & 15;
#pragma unroll
    for (int ks = 0; ks < 8; ++ks) {
        f16x8 a = *(const f16x8*)&sA[arow * LDA1 + ks * 32 + (l >> 4) * 8];
#pragma unroll
        for (int j = 0; j < 2; ++j) {
            const int nt = 2 * w + j;
            f16x8 bb = *(const f16x8*)&Bp1[((size_t)(ks * 8 + nt) * 64 + l) * 8];
            acc[j] = __builtin_amdgcn_mfma_f32_16x16x32_f16(a, bb, acc[j], 0, 0, 0);
        }
    }
    const int r0 = (l >> 4) * 4, cl = l & 15;
#pragma unroll
    for (int j = 0; j < 2; ++j) {
        const int col = (2 * w + j) * 16 + cl;
#pragma unroll
        for (int r = 0; r < 4; ++r) {
            size_t o = (size_t)(node0 + r0 + r) * D_ + col;
            float v = acc[j][r];
            baseh[o] = f2h(v);
            t1[o]    = f2h(fast_tanh(v));
        }
    }
}

__global__ __launch_bounds__(256) void fb_gemm2(const short* __restrict__ t1,
                                                const int* __restrict__ nbr,
                                                const short* __restrict__ Bp2,
                                                const short* __restrict__ baseh,
                                                const float* __restrict__ mask,
                                                const float* __restrict__ w2,
                                                float* __restrict__ out) {
    __shared__ short sA[NPB * LDA2];
    __shared__ int sIdx[NPB * 16];
    __shared__ float pred[128];
    __shared__ float smask[NPB];
    const int tid = threadIdx.x;
    const int blk = fb_swz();
    const int b = blk >> 5;
    const int node0 = blk * NPB;

    if (tid < 64) *(int4*)&sIdx[tid * 4] = *(const int4*)&nbr[(size_t)node0 * 16 + tid * 4];
    if (tid >= 64 && tid < 64 + NPB) smask[tid - 64] = mask[node0 + tid - 64];
    __syncthreads();

    const int row = tid >> 4, lg = tid & 15;
    {
        int idxr[16];
#pragma unroll
        for (int q = 0; q < 4; ++q) *(int4*)&idxr[q * 4] = *(const int4*)&sIdx[row * 16 + q * 4];
        const char* tB = (const char*)t1 + (size_t)b * N_ * D_ * 2 + lg * 16;
        unsigned a0 = 0, a1 = 0, a2 = 0, a3 = 0;
#pragma unroll
        for (int nb = 0; nb < 16; ++nb) {
            int4 d = *(const int4*)(tB + ((unsigned)idxr[nb] << 8));
            pk_add16(a0, (unsigned)d.x);
            pk_add16(a1, (unsigned)d.y);
            pk_add16(a2, (unsigned)d.z);
            pk_add16(a3, (unsigned)d.w);
        }
        unsigned o[4] = { a0, a1, a2, a3 };
        *(int4*)&sA[row * LDA2 + lg * 8] = *(int4*)o;
    }
    __syncthreads();

    const int w = tid >> 6, l = tid & 63;
    f32x4 acc[2];
    acc[0] = (f32x4)0.f; acc[1] = (f32x4)0.f;
    const int arow = l & 15;
#pragma unroll
    for (int ks = 0; ks < 4; ++ks) {
        f16x8 a = *(const f16x8*)&sA[arow * LDA2 + ks * 32 + (l >> 4) * 8];
#pragma unroll
        for (int j = 0; j < 2; ++j) {
            const int nt = 2 * w + j;
            f16x8 bb = *(const f16x8*)&Bp2[((size_t)(ks * 8 + nt) * 64 + l) * 8];
            acc[j] = __builtin_amdgcn_mfma_f32_16x16x32_f16(a, bb, acc[j], 0, 0, 0);
        }
    }
    const int r0 = (l >> 4) * 4, cl = l & 15;
#pragma unroll
    for (int j = 0; j < 2; ++j) {
        const int col = (2 * w + j) * 16 + cl;
        float s = 0.f;
#pragma unroll
        for (int r = 0; r < 4; ++r) {
            size_t o = (size_t)(node0 + r0 + r) * D_ + col;
            float v = fast_tanh(h2f(baseh[o]) + acc[j][r]);
            s += v * smask[r0 + r];
        }
        s += __shfl_xor(s, 16);
        s += __shfl_xor(s, 32);
        if (l < 16) pred[col] = s;
    }
    __syncthreads();
    if (tid < 128) {
        float a2 = 0.f;
#pragma unroll 4
        for (int f = 0; f < 128; ++f) a2 += pred[f] * w2[f * 128 + tid];
        atomicAdd(&out[b * 128 + tid], a2);
    }
}

extern "C" void kernel_launch(void* const* d_in, const int* in_sizes, int n_in,
                              void* d_out, int out_size, void* d_ws, size_t ws_size,
                              hipStream_t stream) {
    const float* word_embs   = (const float*)d_in[0];
    const int*   neibors     = (const int*)d_in[1];
    const float* lib_embs    = (const float*)d_in[2];
    const int*   neibors_lib = (const int*)d_in[3];
    const float* mask        = (const float*)d_in[4];
    const float* weight      = (const float*)d_in[5];
    const float* weight2     = (const float*)d_in[6];
    const float* enc_w1      = (const float*)d_in[7];
    const float* enc_w2      = (const float*)d_in[8];
    float* out = (float*)d_out;

    char* ws = (char*)d_ws;
    short* baseh = (short*)(ws);                             // 8 MB fp16
    short* t1h   = (short*)(ws + (1u << 23));                // 8 MB
    short* libh  = (short*)(ws + (2u << 23));                // 8 MB
    short* Bp1   = (short*)(ws + (3u << 23));                // 64 KB
    short* Bp2   = (short*)(ws + (3u << 23) + 65536);        // 32 KB

    void* kargs[] = {
        (void*)&word_embs, (void*)&neibors_lib, (void*)&lib_embs, (void*)&neibors,
        (void*)&mask, (void*)&weight2, (void*)&enc_w1, (void*)&weight, (void*)&enc_w2,
        (void*)&libh, (void*)&Bp1, (void*)&Bp2, (void*)&baseh, (void*)&t1h, (void*)&out
    };
    hipError_t err = hipLaunchCooperativeKernel((const void*)fused, dim3(512), dim3(512),
                                                kargs, 0, stream);
    if (err != hipSuccess) {
        // Fallback: proven 3-kernel pipeline
        fb_prep<<<1056, 256, 0, stream>>>(lib_embs, enc_w1, weight, enc_w2, libh, Bp1, Bp2, out);
        fb_gemm1<<<G1F, 256, 0, stream>>>(word_embs, neibors_lib, libh, Bp1, baseh, t1h);
        fb_gemm2<<<G1F, 256, 0, stream>>>(t1h, neibors, Bp2, baseh, mask, weight2, out);
    }
}

// Round 17
// 48.255 us; speedup vs baseline: 7.7665x; 7.7665x over previous
//
#include <hip/hip_runtime.h>
#include <hip/hip_bf16.h>

#define B_   64
#define N_   512
#define D_   128
#define NPB  16                 // nodes per block
#define G1   ((B_*N_)/NPB)      // 2048 blocks

typedef float f32x4  __attribute__((ext_vector_type(4)));
typedef _Float16 f16x8 __attribute__((ext_vector_type(8)));

static __device__ __forceinline__ unsigned pkrtz(float x, float y) {
    return __builtin_bit_cast(unsigned, __builtin_amdgcn_cvt_pkrtz(x, y));
}
static __device__ __forceinline__ short f2h(float x) {
    _Float16 h = (_Float16)x;
    return __builtin_bit_cast(short, h);
}
static __device__ __forceinline__ float h2f(short s) {
    return (float)__builtin_bit_cast(_Float16, s);
}
// tanh(x) = 1 - 2/(e^{2x}+1); exact at +/-inf
static __device__ __forceinline__ float fast_tanh(float x) {
    float e = __expf(2.f * x);
    return 1.f - 2.f * __builtin_amdgcn_rcpf(e + 1.f);
}
// packed fp16x2 add, no unpack needed
static __device__ __forceinline__ void pk_add16(unsigned& acc, unsigned v) {
    asm("v_pk_add_f16 %0, %1, %0" : "+v"(acc) : "v"(v));
}

// ---------------------------------------------------------------------------
// prep: blocks 0..1023: lib fp32 -> fp16 (16 elems/thread)
//       blocks 1024..1055: pack Bp1 = [enc1 ; weight/16] (K=256, fp16 frags),
//                          Bp2 = enc2/16 (K=128); zero d_out.
// frag elem j of lane l, tile nt, step ks = M[ks*32+(l>>4)*8+j][nt*16+(l&15)]
// ---------------------------------------------------------------------------
__global__ __launch_bounds__(256) void prep(const float* __restrict__ lib,
                                            const float* __restrict__ enc1,
                                            const float* __restrict__ wgt,
                                            const float* __restrict__ enc2,
                                            short* __restrict__ libh,
                                            short* __restrict__ Bp1,
                                            short* __restrict__ Bp2,
                                            float* __restrict__ out) {
    const int blk = blockIdx.x;
    if (blk < 1024) {
        const size_t g = ((size_t)blk * 256 + threadIdx.x) * 16;
        unsigned o[8];
#pragma unroll
        for (int q = 0; q < 4; ++q) {
            float4 v = *(const float4*)&lib[g + q * 4];
            o[q * 2]     = pkrtz(v.x, v.y);
            o[q * 2 + 1] = pkrtz(v.z, v.w);
        }
        *(int4*)&libh[g]     = *(int4*)o;
        *(int4*)&libh[g + 8] = *(int4*)(o + 4);
        return;
    }
    int tid = (blk - 1024) * 256 + threadIdx.x;   // 0..8191
    out[tid] = 0.f;                               // B_*D_ = 8192
    short o8[8];
    if (tid < 4096) {
        int l = tid & 63, nt = (tid >> 6) & 7, ks = tid >> 9;   // ks 0..7
        int k0 = ks * 32 + (l >> 4) * 8;
        int col = nt * 16 + (l & 15);
#pragma unroll
        for (int j = 0; j < 8; ++j) {
            int r = k0 + j;
            float v = (r < 128) ? enc1[r * 128 + col] : wgt[(r - 128) * 128 + col] * 0.0625f;
            o8[j] = f2h(v);
        }
        *(int4*)&Bp1[(size_t)tid * 8] = *(int4*)o8;
    } else if (tid < 6144) {
        int t2 = tid - 4096;
        int l = t2 & 63, nt = (t2 >> 6) & 7, ks = t2 >> 9;      // ks 0..3
        int k0 = ks * 32 + (l >> 4) * 8;
        int col = nt * 16 + (l & 15);
#pragma unroll
        for (int j = 0; j < 8; ++j) o8[j] = f2h(enc2[(k0 + j) * 128 + col] * 0.0625f);
        *(int4*)&Bp2[(size_t)t2 * 8] = *(int4*)o8;
    }
}

// XCD-aware swizzle: 2048 blocks, 32 per batch. XCD k <- batches [8k,8k+8).
static __device__ __forceinline__ int swz_blk() {
    const int hw = blockIdx.x;
    return ((hw & 7) << 8) + (hw >> 3);
}

#define LDA1 264   // 256 + 8 pad (fp16 elems)
#define LDA2 136   // 128 + 8 pad

// ---------------------------------------------------------------------------
// gemm1: base = [word | sum_nb lib[idx]] @ [enc1 ; weight/16]  (K=256, f16 MFMA)
//        t1 = tanh(base).  Gather: 16 lanes/row, int4 loads, v_pk_add_f16.
// ---------------------------------------------------------------------------
__global__ __launch_bounds__(256) void gemm1(const float* __restrict__ word,
                                             const int* __restrict__ nbrL,
                                             const short* __restrict__ libh,
                                             const short* __restrict__ Bp1,
                                             short* __restrict__ baseh,
                                             short* __restrict__ t1) {
    __shared__ short sA[NPB * LDA1];
    __shared__ int sIdx[NPB * 16];
    const int tid = threadIdx.x;
    const int blk = swz_blk();
    const int b = blk >> 5;
    const int node0 = blk * NPB;

    if (tid < 64) *(int4*)&sIdx[tid * 4] = *(const int4*)&nbrL[(size_t)node0 * 16 + tid * 4];
    __syncthreads();

    const int row = tid >> 4;        // 0..15
    const int lg  = tid & 15;        // 8-col group

    // stage word row-part (fp32 -> fp16)
    {
        const float* wr = word + (size_t)(node0 + row) * D_ + lg * 8;
        float4 v0 = *(const float4*)&wr[0];
        float4 v1 = *(const float4*)&wr[4];
        unsigned o[4] = { pkrtz(v0.x, v0.y), pkrtz(v0.z, v0.w),
                          pkrtz(v1.x, v1.y), pkrtz(v1.z, v1.w) };
        *(int4*)&sA[row * LDA1 + lg * 8] = *(int4*)o;
    }

    // gather-sum neighbors: 16 x (1 lshl_add + 1 load_dwordx4 + 4 pk_add)
    {
        int idxr[16];
#pragma unroll
        for (int q = 0; q < 4; ++q) *(int4*)&idxr[q * 4] = *(const int4*)&sIdx[row * 16 + q * 4];
        const char* libB = (const char*)libh + (size_t)b * N_ * D_ * 2 + lg * 16;
        unsigned a0 = 0, a1 = 0, a2 = 0, a3 = 0;
#pragma unroll
        for (int nb = 0; nb < 16; ++nb) {
            int4 d = *(const int4*)(libB + ((unsigned)idxr[nb] << 8));
            pk_add16(a0, (unsigned)d.x);
            pk_add16(a1, (unsigned)d.y);
            pk_add16(a2, (unsigned)d.z);
            pk_add16(a3, (unsigned)d.w);
        }
        unsigned o[4] = { a0, a1, a2, a3 };   // raw sums; /16 folded into Bp1
        *(int4*)&sA[row * LDA1 + 128 + lg * 8] = *(int4*)o;
    }
    __syncthreads();

    // MFMA K=256: wave w -> col tiles 2w, 2w+1
    const int w = tid >> 6, l = tid & 63;
    f32x4 acc[2];
    acc[0] = (f32x4)0.f; acc[1] = (f32x4)0.f;
    const int arow = l & 15;
#pragma unroll
    for (int ks = 0; ks < 8; ++ks) {
        f16x8 a = *(const f16x8*)&sA[arow * LDA1 + ks * 32 + (l >> 4) * 8];
#pragma unroll
        for (int j = 0; j < 2; ++j) {
            const int nt = 2 * w + j;
            f16x8 bb = *(const f16x8*)&Bp1[((size_t)(ks * 8 + nt) * 64 + l) * 8];
            acc[j] = __builtin_amdgcn_mfma_f32_16x16x32_f16(a, bb, acc[j], 0, 0, 0);
        }
    }

    const int r0 = (l >> 4) * 4;
    const int cl = l & 15;
#pragma unroll
    for (int j = 0; j < 2; ++j) {
        const int col = (2 * w + j) * 16 + cl;
#pragma unroll
        for (int r = 0; r < 4; ++r) {
            size_t o = (size_t)(node0 + r0 + r) * D_ + col;
            float v = acc[j][r];
            baseh[o] = f2h(v);
            t1[o]    = f2h(fast_tanh(v));
        }
    }
}

// ---------------------------------------------------------------------------
// gemm2: t2 = tanh(base + (sum_nb t1[idx]) @ (enc2/16));
//        out[b] += (sum_n mask*t2) @ weight2
// ---------------------------------------------------------------------------
__global__ __launch_bounds__(256) void gemm2(const short* __restrict__ t1,
                                             const int* __restrict__ nbr,
                                             const short* __restrict__ Bp2,
                                             const short* __restrict__ baseh,
                                             const float* __restrict__ mask,
                                             const float* __restrict__ w2,
                                             float* __restrict__ out) {
    __shared__ short sA[NPB * LDA2];
    __shared__ int sIdx[NPB * 16];
    __shared__ float pred[128];
    __shared__ float smask[NPB];
    const int tid = threadIdx.x;
    const int blk = swz_blk();
    const int b = blk >> 5;
    const int node0 = blk * NPB;

    if (tid < 64) *(int4*)&sIdx[tid * 4] = *(const int4*)&nbr[(size_t)node0 * 16 + tid * 4];
    if (tid >= 64 && tid < 64 + NPB) smask[tid - 64] = mask[node0 + tid - 64];
    __syncthreads();

    const int row = tid >> 4;
    const int lg  = tid & 15;
    {
        int idxr[16];
#pragma unroll
        for (int q = 0; q < 4; ++q) *(int4*)&idxr[q * 4] = *(const int4*)&sIdx[row * 16 + q * 4];
        const char* tB = (const char*)t1 + (size_t)b * N_ * D_ * 2 + lg * 16;
        unsigned a0 = 0, a1 = 0, a2 = 0, a3 = 0;
#pragma unroll
        for (int nb = 0; nb < 16; ++nb) {
            int4 d = *(const int4*)(tB + ((unsigned)idxr[nb] << 8));
            pk_add16(a0, (unsigned)d.x);
            pk_add16(a1, (unsigned)d.y);
            pk_add16(a2, (unsigned)d.z);
            pk_add16(a3, (unsigned)d.w);
        }
        unsigned o[4] = { a0, a1, a2, a3 };   // /16 folded into Bp2
        *(int4*)&sA[row * LDA2 + lg * 8] = *(int4*)o;
    }
    __syncthreads();

    const int w = tid >> 6, l = tid & 63;
    f32x4 acc[2];
    acc[0] = (f32x4)0.f; acc[1] = (f32x4)0.f;
    const int arow = l & 15;
#pragma unroll
    for (int ks = 0; ks < 4; ++ks) {
        f16x8 a = *(const f16x8*)&sA[arow * LDA2 + ks * 32 + (l >> 4) * 8];
#pragma unroll
        for (int j = 0; j < 2; ++j) {
            const int nt = 2 * w + j;
            f16x8 bb = *(const f16x8*)&Bp2[((size_t)(ks * 8 + nt) * 64 + l) * 8];
            acc[j] = __builtin_amdgcn_mfma_f32_16x16x32_f16(a, bb, acc[j], 0, 0, 0);
        }
    }

    const int r0 = (l >> 4) * 4;
    const int cl = l & 15;
#pragma unroll
    for (int j = 0; j < 2; ++j) {
        const int col = (2 * w + j) * 16 + cl;
        float s = 0.f;
#pragma unroll
        for (int r = 0; r < 4; ++r) {
            size_t o = (size_t)(node0 + r0 + r) * D_ + col;
            float v = fast_tanh(h2f(baseh[o]) + acc[j][r]);
            s += v * smask[r0 + r];
        }
        s += __shfl_xor(s, 16);
        s += __shfl_xor(s, 32);
        if (l < 16) pred[col] = s;
    }
    __syncthreads();
    if (tid < 128) {
        float a2 = 0.f;
#pragma unroll 4
        for (int f = 0; f < 128; ++f) a2 += pred[f] * w2[f * 128 + tid];
        atomicAdd(&out[b * 128 + tid], a2);
    }
}

extern "C" void kernel_launch(void* const* d_in, const int* in_sizes, int n_in,
                              void* d_out, int out_size, void* d_ws, size_t ws_size,
                              hipStream_t stream) {
    const float* word_embs   = (const float*)d_in[0];
    const int*   neibors     = (const int*)d_in[1];
    const float* lib_embs    = (const float*)d_in[2];
    const int*   neibors_lib = (const int*)d_in[3];
    const float* mask        = (const float*)d_in[4];
    const float* weight      = (const float*)d_in[5];
    const float* weight2     = (const float*)d_in[6];
    const float* enc_w1      = (const float*)d_in[7];
    const float* enc_w2      = (const float*)d_in[8];
    float* out = (float*)d_out;

    char* ws = (char*)d_ws;
    short* baseh = (short*)(ws);                             // 8 MB fp16
    short* t1    = (short*)(ws + (1u << 23));                // 8 MB fp16
    short* libh  = (short*)(ws + (2u << 23));                // 8 MB fp16
    short* Bp1   = (short*)(ws + (3u << 23));                // 64 KB
    short* Bp2   = (short*)(ws + (3u << 23) + 65536);        // 32 KB

    prep<<<1056, 256, 0, stream>>>(lib_embs, enc_w1, weight, enc_w2, libh, Bp1, Bp2, out);
    gemm1<<<G1, 256, 0, stream>>>(word_embs, neibors_lib, libh, Bp1, baseh, t1);
    gemm2<<<G1, 256, 0, stream>>>(t1, neibors, Bp2, baseh, mask, weight2, out);
}